// Round 2
// baseline (791.972 us; speedup 1.0000x reference)
//
#include <hip/hip_runtime.h>
#include <math.h>

#define NH   8
#define HW   32
#define LSEQ 2048
#define EMB  256
#define BB   2

// ---------------------------------------------------------------------------
// QKV projection: t[m,f] = sum_e X[m,e] * Wp[f,e], scatter into Q/K/V
// [b][h][l][32], Q pre-scaled.  M=4096, N=768, K=256.
// Tile 128x64, 256 threads, 8x4 micro, k-step 64, reg-prefetched.
// ---------------------------------------------------------------------------
__global__ __launch_bounds__(256) void qkv_gemm(
    const float* __restrict__ X, const float* __restrict__ Wp,
    float* __restrict__ Qw, float* __restrict__ Kw, float* __restrict__ Vw) {
  __shared__ __attribute__((aligned(16))) float As[64 * 132];  // [k][m] pad
  __shared__ __attribute__((aligned(16))) float Bs[64 * 68];   // [k][n] pad
  const int t = threadIdx.x;
  const int tm = t >> 4, tn = t & 15;
  const int m0 = blockIdx.y * 128, n0 = blockIdx.x * 64;
  float acc[8][4] = {};
  float4 areg[8], breg[4];
#pragma unroll
  for (int u = 0; u < 8; ++u) {
    int fi = t + u * 256; int m = fi >> 4, k4 = fi & 15;
    areg[u] = *(const float4*)&X[(m0 + m) * 256 + k4 * 4];
  }
#pragma unroll
  for (int u = 0; u < 4; ++u) {
    int fi = t + u * 256; int n = fi >> 4, k4 = fi & 15;
    breg[u] = *(const float4*)&Wp[(n0 + n) * 256 + k4 * 4];
  }
#pragma unroll 1
  for (int s = 0; s < 4; ++s) {
    __syncthreads();
#pragma unroll
    for (int u = 0; u < 8; ++u) {
      int fi = t + u * 256; int m = fi >> 4, k4 = fi & 15;
      As[(k4 * 4 + 0) * 132 + m] = areg[u].x;
      As[(k4 * 4 + 1) * 132 + m] = areg[u].y;
      As[(k4 * 4 + 2) * 132 + m] = areg[u].z;
      As[(k4 * 4 + 3) * 132 + m] = areg[u].w;
    }
#pragma unroll
    for (int u = 0; u < 4; ++u) {
      int fi = t + u * 256; int n = fi >> 4, k4 = fi & 15;
      Bs[(k4 * 4 + 0) * 68 + n] = breg[u].x;
      Bs[(k4 * 4 + 1) * 68 + n] = breg[u].y;
      Bs[(k4 * 4 + 2) * 68 + n] = breg[u].z;
      Bs[(k4 * 4 + 3) * 68 + n] = breg[u].w;
    }
    if (s < 3) {
      int k0 = (s + 1) * 64;
#pragma unroll
      for (int u = 0; u < 8; ++u) {
        int fi = t + u * 256; int m = fi >> 4, k4 = fi & 15;
        areg[u] = *(const float4*)&X[(m0 + m) * 256 + k0 + k4 * 4];
      }
#pragma unroll
      for (int u = 0; u < 4; ++u) {
        int fi = t + u * 256; int n = fi >> 4, k4 = fi & 15;
        breg[u] = *(const float4*)&Wp[(n0 + n) * 256 + k0 + k4 * 4];
      }
    }
    __syncthreads();
#pragma unroll 4
    for (int kk = 0; kk < 64; ++kk) {
      float4 a0 = *(const float4*)&As[kk * 132 + tm * 8];
      float4 a1 = *(const float4*)&As[kk * 132 + tm * 8 + 4];
      float4 bv = *(const float4*)&Bs[kk * 68 + tn * 4];
      float am[8] = {a0.x, a0.y, a0.z, a0.w, a1.x, a1.y, a1.z, a1.w};
      float bn[4] = {bv.x, bv.y, bv.z, bv.w};
#pragma unroll
      for (int i = 0; i < 8; ++i)
#pragma unroll
        for (int j = 0; j < 4; ++j) acc[i][j] = fmaf(am[i], bn[j], acc[i][j]);
    }
  }
  const float qscale = 0.17677669529663687f;  // 32^-0.5
#pragma unroll
  for (int i = 0; i < 8; ++i) {
    int m = m0 + tm * 8 + i;
    int bb = m >> 11, ll = m & 2047;
#pragma unroll
    for (int j = 0; j < 4; ++j) {
      int f = n0 + tn * 4 + j;
      int h = f / 96, r = f - h * 96;
      int base = ((bb * NH + h) * LSEQ + ll) * HW;
      float v = acc[i][j];
      if (r < 32)       Qw[base + r]      = v * qscale;
      else if (r < 64)  Kw[base + r - 32] = v;
      else              Vw[base + r - 64] = v;
    }
  }
}

// ---------------------------------------------------------------------------
// Flash attention with pair bias, v2.
// Block = (b, 16 q-rows, 4 heads).  Grid 512 -> 2 blocks/CU.  Sibling blocks
// (the two h-halves of one (b,qt)) are 8 apart in blockIdx.x => same XCD L2,
// each consumes half of every bias cache line.
// Wave = one head.  k-tile = 32, 2 barriers per tile, next tile's K/V/bias
// prefetched into registers during compute.
// Lane l: qg=l>>4 (4 q's), S-phase: e=(l>>3)&1 (c-half, interleaved c4=2cc+e),
// kg=l&7 (4 k's: k=8j+kg).  PV: kgp=(l>>2)&3 (k mod 4), cg=l&3 (8 c's).
// ---------------------------------------------------------------------------
__global__ __launch_bounds__(256, 2) void attn(
    const float* __restrict__ Qg, const float* __restrict__ Kg,
    const float* __restrict__ Vg, const float* __restrict__ Bias,
    float* __restrict__ Y) {
  __shared__ __attribute__((aligned(16))) float Qs[4 * 16 * 36];   // [h][q][c] stride 36
  __shared__ __attribute__((aligned(16))) float Ks[4 * 32 * 40];   // [h][k][c] stride 40
  __shared__ __attribute__((aligned(16))) float Vs[4 * 32 * 36];   // [h][k][c] stride 36
  __shared__ __attribute__((aligned(16))) float Bls[16 * 132];     // [q][k][h4] strides 132/4
  __shared__ __attribute__((aligned(16))) float Pt[4 * 32 * 24];   // [h][k][q] stride 24

  const int x = blockIdx.x;
  const int p = ((x >> 4) << 3) | (x & 7);
  const int hh = (x >> 3) & 1;
  const int b = p & 1;
  const int q0g = (p >> 1) * 16;

  const int t = threadIdx.x;
  const int h = t >> 6;          // wave id = local head
  const int l = t & 63;
  const int qg = l >> 4;
  const int e = (l >> 3) & 1;
  const int kg = l & 7;
  const int kgp = (l >> 2) & 3;
  const int cg = l & 3;
  const int q0 = qg * 4;

  // ---- stage Q once ----
#pragma unroll
  for (int j = 0; j < 2; ++j) {
    int fi = t + j * 256;
    int hh_ = fi >> 7, q = (fi >> 3) & 15, c4 = fi & 7;
    float4 v = *(const float4*)&Qg[((b * NH + hh * 4 + hh_) * LSEQ + q0g + q) * HW + c4 * 4];
    *(float4*)&Qs[hh_ * 576 + q * 36 + c4 * 4] = v;
  }

  float4 kreg[4], vreg[4], breg[2];
  // prefetch tile 0
#pragma unroll
  for (int j = 0; j < 4; ++j) {
    int fi = t + j * 256;
    int hh_ = fi >> 8, k = (fi >> 3) & 31, c4 = fi & 7;
    const int row = (b * NH + hh * 4 + hh_) * LSEQ + k;
    kreg[j] = *(const float4*)&Kg[row * HW + c4 * 4];
    vreg[j] = *(const float4*)&Vg[row * HW + c4 * 4];
  }
#pragma unroll
  for (int j = 0; j < 2; ++j) {
    int fi = t + j * 256;
    int q = fi >> 5, k = fi & 31;
    breg[j] = *(const float4*)&Bias[((size_t)(b * LSEQ + q0g + q) * LSEQ + k) * NH + hh * 4];
  }

  float m_i[4], l_i[4], o[4][8];
#pragma unroll
  for (int i = 0; i < 4; ++i) {
    m_i[i] = -1e30f; l_i[i] = 0.f;
#pragma unroll
    for (int j = 0; j < 8; ++j) o[i][j] = 0.f;
  }

#pragma unroll 1
  for (int tile = 0; tile < 64; ++tile) {
    __syncthreads();  // previous tile's LDS reads complete
#pragma unroll
    for (int j = 0; j < 4; ++j) {
      int fi = t + j * 256;
      int hh_ = fi >> 8, k = (fi >> 3) & 31, c4 = fi & 7;
      *(float4*)&Ks[hh_ * 1280 + k * 40 + c4 * 4] = kreg[j];
      *(float4*)&Vs[hh_ * 1152 + k * 36 + c4 * 4] = vreg[j];
    }
#pragma unroll
    for (int j = 0; j < 2; ++j) {
      int fi = t + j * 256;
      int q = fi >> 5, k = fi & 31;
      *(float4*)&Bls[q * 132 + k * 4] = breg[j];
    }
    if (tile < 63) {
      const int kb = (tile + 1) * 32;
#pragma unroll
      for (int j = 0; j < 4; ++j) {
        int fi = t + j * 256;
        int hh_ = fi >> 8, k = (fi >> 3) & 31, c4 = fi & 7;
        const int row = (b * NH + hh * 4 + hh_) * LSEQ + kb + k;
        kreg[j] = *(const float4*)&Kg[row * HW + c4 * 4];
        vreg[j] = *(const float4*)&Vg[row * HW + c4 * 4];
      }
#pragma unroll
      for (int j = 0; j < 2; ++j) {
        int fi = t + j * 256;
        int q = fi >> 5, k = fi & 31;
        breg[j] = *(const float4*)&Bias[((size_t)(b * LSEQ + q0g + q) * LSEQ + kb + k) * NH + hh * 4];
      }
    }
    __syncthreads();  // staging visible

    // ---- S = Q K^T : 4q x 4k scalars, contraction split over e lanes ----
    float s[4][4];
#pragma unroll
    for (int i = 0; i < 4; ++i)
#pragma unroll
      for (int j = 0; j < 4; ++j) s[i][j] = 0.f;
#pragma unroll
    for (int cc = 0; cc < 4; ++cc) {
      int c4 = cc * 2 + e;  // interleaved c-half
      float4 kv[4];
#pragma unroll
      for (int j = 0; j < 4; ++j)
        kv[j] = *(const float4*)&Ks[h * 1280 + (j * 8 + kg) * 40 + c4 * 4];
#pragma unroll
      for (int i = 0; i < 4; ++i) {
        float4 qv = *(const float4*)&Qs[h * 576 + (q0 + i) * 36 + c4 * 4];
#pragma unroll
        for (int j = 0; j < 4; ++j) {
          s[i][j] = fmaf(qv.x, kv[j].x, s[i][j]);
          s[i][j] = fmaf(qv.y, kv[j].y, s[i][j]);
          s[i][j] = fmaf(qv.z, kv[j].z, s[i][j]);
          s[i][j] = fmaf(qv.w, kv[j].w, s[i][j]);
        }
      }
    }
#pragma unroll
    for (int i = 0; i < 4; ++i)
#pragma unroll
      for (int j = 0; j < 4; ++j) {
        s[i][j] += __shfl_xor(s[i][j], 8, 64);  // e-reduce
        s[i][j] += Bls[(q0 + i) * 132 + (j * 8 + kg) * 4 + h];
      }

    // ---- online softmax (row group = 16 lanes: e x kg) ----
    float alpha[4];
#pragma unroll
    for (int i = 0; i < 4; ++i) {
      float mx = fmaxf(fmaxf(s[i][0], s[i][1]), fmaxf(s[i][2], s[i][3]));
      mx = fmaxf(mx, __shfl_xor(mx, 1, 64));
      mx = fmaxf(mx, __shfl_xor(mx, 2, 64));
      mx = fmaxf(mx, __shfl_xor(mx, 4, 64));
      float mnew = fmaxf(m_i[i], mx);
      float ps = 0.f;
#pragma unroll
      for (int j = 0; j < 4; ++j) { s[i][j] = __expf(s[i][j] - mnew); ps += s[i][j]; }
      ps += __shfl_xor(ps, 1, 64);
      ps += __shfl_xor(ps, 2, 64);
      ps += __shfl_xor(ps, 4, 64);
      alpha[i] = __expf(m_i[i] - mnew);
      l_i[i] = l_i[i] * alpha[i] + ps;
      m_i[i] = mnew;
    }

    // ---- write P transposed (wave-private region; same-wave LDS order) ----
    if (e == 0) {
#pragma unroll
      for (int j = 0; j < 4; ++j) {
        float4 pv = make_float4(s[0][j], s[1][j], s[2][j], s[3][j]);
        *(float4*)&Pt[h * 768 + (j * 8 + kg) * 24 + q0] = pv;
      }
    }

    // ---- O update: 4q x 8c, k split over kgp lanes ----
#pragma unroll
    for (int i = 0; i < 4; ++i) {
      float a = alpha[i];
#pragma unroll
      for (int j = 0; j < 8; ++j) o[i][j] *= a;
    }
#pragma unroll
    for (int tt = 0; tt < 8; ++tt) {
      int k = tt * 4 + kgp;
      float4 pt = *(const float4*)&Pt[h * 768 + k * 24 + q0];
      float4 v0 = *(const float4*)&Vs[h * 1152 + k * 36 + cg * 8];
      float4 v1 = *(const float4*)&Vs[h * 1152 + k * 36 + cg * 8 + 4];
      float pa[4] = {pt.x, pt.y, pt.z, pt.w};
#pragma unroll
      for (int i = 0; i < 4; ++i) {
        o[i][0] = fmaf(pa[i], v0.x, o[i][0]);
        o[i][1] = fmaf(pa[i], v0.y, o[i][1]);
        o[i][2] = fmaf(pa[i], v0.z, o[i][2]);
        o[i][3] = fmaf(pa[i], v0.w, o[i][3]);
        o[i][4] = fmaf(pa[i], v1.x, o[i][4]);
        o[i][5] = fmaf(pa[i], v1.y, o[i][5]);
        o[i][6] = fmaf(pa[i], v1.z, o[i][6]);
        o[i][7] = fmaf(pa[i], v1.w, o[i][7]);
      }
    }
  }

  // ---- reduce over kgp lanes, normalize, write ----
#pragma unroll
  for (int i = 0; i < 4; ++i)
#pragma unroll
    for (int j = 0; j < 8; ++j) {
      float v = o[i][j];
      v += __shfl_xor(v, 4, 64);
      v += __shfl_xor(v, 8, 64);
      o[i][j] = v;
    }
  if (kgp == 0) {
#pragma unroll
    for (int i = 0; i < 4; ++i) {
      float inv = 1.0f / l_i[i];
      float4 r0 = make_float4(o[i][0] * inv, o[i][1] * inv, o[i][2] * inv, o[i][3] * inv);
      float4 r1 = make_float4(o[i][4] * inv, o[i][5] * inv, o[i][6] * inv, o[i][7] * inv);
      float* yp = &Y[(b * LSEQ + q0g + q0 + i) * EMB + (hh * 4 + h) * HW + cg * 8];
      *(float4*)yp = r0;
      *(float4*)(yp + 4) = r1;
    }
  }
}

// ---------------------------------------------------------------------------
// Output projection: Out[m,n] = sum_e Y[m,e]*Wo[n,e] + bo[n].  M=4096,N=256,K=256.
// Tile 64x64, k-step 64, 4x4 micro, reg-prefetched.
// ---------------------------------------------------------------------------
__global__ __launch_bounds__(256) void out_gemm(
    const float* __restrict__ Yg, const float* __restrict__ Wo,
    const float* __restrict__ bo, float* __restrict__ Out) {
  __shared__ __attribute__((aligned(16))) float As[64 * 68];  // [k][m]
  __shared__ __attribute__((aligned(16))) float Bs[64 * 68];  // [k][n]
  const int t = threadIdx.x;
  const int tm = t >> 4, tn = t & 15;
  const int m0 = blockIdx.y * 64, n0 = blockIdx.x * 64;
  float acc[4][4] = {};
  float4 areg[4], breg[4];
#pragma unroll
  for (int u = 0; u < 4; ++u) {
    int fi = t + u * 256; int m = fi >> 4, k4 = fi & 15;
    areg[u] = *(const float4*)&Yg[(m0 + m) * 256 + k4 * 4];
    breg[u] = *(const float4*)&Wo[(n0 + m) * 256 + k4 * 4];
  }
#pragma unroll 1
  for (int s = 0; s < 4; ++s) {
    __syncthreads();
#pragma unroll
    for (int u = 0; u < 4; ++u) {
      int fi = t + u * 256; int m = fi >> 4, k4 = fi & 15;
      As[(k4 * 4 + 0) * 68 + m] = areg[u].x;
      As[(k4 * 4 + 1) * 68 + m] = areg[u].y;
      As[(k4 * 4 + 2) * 68 + m] = areg[u].z;
      As[(k4 * 4 + 3) * 68 + m] = areg[u].w;
      Bs[(k4 * 4 + 0) * 68 + m] = breg[u].x;
      Bs[(k4 * 4 + 1) * 68 + m] = breg[u].y;
      Bs[(k4 * 4 + 2) * 68 + m] = breg[u].z;
      Bs[(k4 * 4 + 3) * 68 + m] = breg[u].w;
    }
    if (s < 3) {
      int k0 = (s + 1) * 64;
#pragma unroll
      for (int u = 0; u < 4; ++u) {
        int fi = t + u * 256; int m = fi >> 4, k4 = fi & 15;
        areg[u] = *(const float4*)&Yg[(m0 + m) * 256 + k0 + k4 * 4];
        breg[u] = *(const float4*)&Wo[(n0 + m) * 256 + k0 + k4 * 4];
      }
    }
    __syncthreads();
#pragma unroll 4
    for (int kk = 0; kk < 64; ++kk) {
      float4 av = *(const float4*)&As[kk * 68 + tm * 4];
      float4 bv = *(const float4*)&Bs[kk * 68 + tn * 4];
      float am[4] = {av.x, av.y, av.z, av.w};
      float bn[4] = {bv.x, bv.y, bv.z, bv.w};
#pragma unroll
      for (int i = 0; i < 4; ++i)
#pragma unroll
        for (int j = 0; j < 4; ++j) acc[i][j] = fmaf(am[i], bn[j], acc[i][j]);
    }
  }
#pragma unroll
  for (int i = 0; i < 4; ++i) {
    int m = m0 + tm * 4 + i;
#pragma unroll
    for (int j = 0; j < 4; ++j) {
      int n = n0 + tn * 4 + j;
      Out[m * 256 + n] = acc[i][j] + bo[n];
    }
  }
}

extern "C" void kernel_launch(void* const* d_in, const int* in_sizes, int n_in,
                              void* d_out, int out_size, void* d_ws, size_t ws_size,
                              hipStream_t stream) {
  const float* X    = (const float*)d_in[0];
  const float* Bias = (const float*)d_in[1];
  const float* Wp   = (const float*)d_in[2];
  const float* Wo   = (const float*)d_in[3];
  const float* bo   = (const float*)d_in[4];
  float* Out = (float*)d_out;

  const size_t qkv_elems = (size_t)BB * NH * LSEQ * HW;  // 1,048,576
  float* Qw = (float*)d_ws;
  float* Kw = Qw + qkv_elems;
  float* Vw = Kw + qkv_elems;
  float* Yw = Vw + qkv_elems;  // 4096 x 256

  qkv_gemm<<<dim3(12, 32), 256, 0, stream>>>(X, Wp, Qw, Kw, Vw);
  attn<<<dim3(512), 256, 0, stream>>>(Qw, Kw, Vw, Bias, Yw);
  out_gemm<<<dim3(4, 64), 256, 0, stream>>>(Yw, Wo, bo, Out);
}

// Round 3
// 589.577 us; speedup vs baseline: 1.3433x; 1.3433x over previous
//
#include <hip/hip_runtime.h>
#include <math.h>

#define NH   8
#define HW   32
#define LSEQ 2048
#define EMB  256
#define BB   2

typedef short bf16x8 __attribute__((ext_vector_type(8)));
typedef float f32x4  __attribute__((ext_vector_type(4)));

__device__ __forceinline__ unsigned short f2bf(float x) {  // RNE
  union { float f; unsigned u; } v; v.f = x;
  unsigned r = v.u + 0x7fffu + ((v.u >> 16) & 1u);
  return (unsigned short)(r >> 16);
}
__device__ __forceinline__ float bf2f(unsigned short h) {
  union { float f; unsigned u; } v; v.u = ((unsigned)h) << 16;
  return v.f;
}

// ---------------------------------------------------------------------------
// QKV projection -> bf16 hi/lo planes.
// Qh/Ql, Kh/Kl: [b][h][l][32] (Q pre-scaled by 32^-0.5).
// Vth/Vtl: [b][h][c=32][l=2048]  (transposed, for MFMA A-frag direct loads).
// M=4096, N=768, K=256.  Tile 128x64, 256 thr, 8x4 micro, k-step 64.
// ---------------------------------------------------------------------------
__global__ __launch_bounds__(256) void qkv_gemm(
    const float* __restrict__ X, const float* __restrict__ Wp,
    unsigned short* __restrict__ Qh, unsigned short* __restrict__ Ql,
    unsigned short* __restrict__ Kh, unsigned short* __restrict__ Kl,
    unsigned short* __restrict__ Vth, unsigned short* __restrict__ Vtl) {
  __shared__ __attribute__((aligned(16))) float As[64 * 132];  // [k][m]
  __shared__ __attribute__((aligned(16))) float Bs[64 * 68];   // [k][n]
  const int t = threadIdx.x;
  const int tm = t >> 4, tn = t & 15;
  const int m0 = blockIdx.y * 128, n0 = blockIdx.x * 64;
  float acc[8][4] = {};
  float4 areg[8], breg[4];
#pragma unroll
  for (int u = 0; u < 8; ++u) {
    int fi = t + u * 256; int m = fi >> 4, k4 = fi & 15;
    areg[u] = *(const float4*)&X[(m0 + m) * 256 + k4 * 4];
  }
#pragma unroll
  for (int u = 0; u < 4; ++u) {
    int fi = t + u * 256; int n = fi >> 4, k4 = fi & 15;
    breg[u] = *(const float4*)&Wp[(n0 + n) * 256 + k4 * 4];
  }
#pragma unroll 1
  for (int s = 0; s < 4; ++s) {
    __syncthreads();
#pragma unroll
    for (int u = 0; u < 8; ++u) {
      int fi = t + u * 256; int m = fi >> 4, k4 = fi & 15;
      As[(k4 * 4 + 0) * 132 + m] = areg[u].x;
      As[(k4 * 4 + 1) * 132 + m] = areg[u].y;
      As[(k4 * 4 + 2) * 132 + m] = areg[u].z;
      As[(k4 * 4 + 3) * 132 + m] = areg[u].w;
    }
#pragma unroll
    for (int u = 0; u < 4; ++u) {
      int fi = t + u * 256; int n = fi >> 4, k4 = fi & 15;
      Bs[(k4 * 4 + 0) * 68 + n] = breg[u].x;
      Bs[(k4 * 4 + 1) * 68 + n] = breg[u].y;
      Bs[(k4 * 4 + 2) * 68 + n] = breg[u].z;
      Bs[(k4 * 4 + 3) * 68 + n] = breg[u].w;
    }
    if (s < 3) {
      int k0 = (s + 1) * 64;
#pragma unroll
      for (int u = 0; u < 8; ++u) {
        int fi = t + u * 256; int m = fi >> 4, k4 = fi & 15;
        areg[u] = *(const float4*)&X[(m0 + m) * 256 + k0 + k4 * 4];
      }
#pragma unroll
      for (int u = 0; u < 4; ++u) {
        int fi = t + u * 256; int n = fi >> 4, k4 = fi & 15;
        breg[u] = *(const float4*)&Wp[(n0 + n) * 256 + k0 + k4 * 4];
      }
    }
    __syncthreads();
#pragma unroll 4
    for (int kk = 0; kk < 64; ++kk) {
      float4 a0 = *(const float4*)&As[kk * 132 + tm * 8];
      float4 a1 = *(const float4*)&As[kk * 132 + tm * 8 + 4];
      float4 bv = *(const float4*)&Bs[kk * 68 + tn * 4];
      float am[8] = {a0.x, a0.y, a0.z, a0.w, a1.x, a1.y, a1.z, a1.w};
      float bn[4] = {bv.x, bv.y, bv.z, bv.w};
#pragma unroll
      for (int i = 0; i < 8; ++i)
#pragma unroll
        for (int j = 0; j < 4; ++j) acc[i][j] = fmaf(am[i], bn[j], acc[i][j]);
    }
  }
  // ---- epilogue: split to bf16 hi/lo and scatter ----
  const float qscale = 0.17677669529663687f;  // 32^-0.5
  const int f0 = n0 + tn * 4;
  const int hd = f0 / 96;
  const int r0 = f0 - hd * 96;               // 4-aligned, never crosses 32
  const int bb = m0 >> 11;
  const int l0 = (m0 & 2047) + tm * 8;
  if (r0 < 64) {
    const int c0 = (r0 < 32) ? r0 : r0 - 32;
    const float sc = (r0 < 32) ? qscale : 1.0f;
    unsigned short* dh = (r0 < 32) ? Qh : Kh;
    unsigned short* dl = (r0 < 32) ? Ql : Kl;
#pragma unroll
    for (int i = 0; i < 8; ++i) {
      unsigned short hs[4], ls[4];
#pragma unroll
      for (int j = 0; j < 4; ++j) {
        float v = acc[i][j] * sc;
        hs[j] = f2bf(v);
        ls[j] = f2bf(v - bf2f(hs[j]));
      }
      size_t idx = ((size_t)(bb * NH + hd) * LSEQ + l0 + i) * HW + c0;
      uint2 hv = make_uint2((unsigned)hs[0] | ((unsigned)hs[1] << 16),
                            (unsigned)hs[2] | ((unsigned)hs[3] << 16));
      uint2 lv = make_uint2((unsigned)ls[0] | ((unsigned)ls[1] << 16),
                            (unsigned)ls[2] | ((unsigned)ls[3] << 16));
      *(uint2*)&dh[idx] = hv;
      *(uint2*)&dl[idx] = lv;
    }
  } else {
    const int c0 = r0 - 64;
#pragma unroll
    for (int j = 0; j < 4; ++j) {
      unsigned short hs[8], ls[8];
#pragma unroll
      for (int i = 0; i < 8; ++i) {
        float v = acc[i][j];
        hs[i] = f2bf(v);
        ls[i] = f2bf(v - bf2f(hs[i]));
      }
      size_t idx = ((size_t)(bb * NH + hd) * HW + c0 + j) * LSEQ + l0;
      uint4 hv = make_uint4((unsigned)hs[0] | ((unsigned)hs[1] << 16),
                            (unsigned)hs[2] | ((unsigned)hs[3] << 16),
                            (unsigned)hs[4] | ((unsigned)hs[5] << 16),
                            (unsigned)hs[6] | ((unsigned)hs[7] << 16));
      uint4 lv = make_uint4((unsigned)ls[0] | ((unsigned)ls[1] << 16),
                            (unsigned)ls[2] | ((unsigned)ls[3] << 16),
                            (unsigned)ls[4] | ((unsigned)ls[5] << 16),
                            (unsigned)ls[6] | ((unsigned)ls[7] << 16));
      *(uint4*)&Vth[idx] = hv;
      *(uint4*)&Vtl[idx] = lv;
    }
  }
}

// ---------------------------------------------------------------------------
// MFMA flash attention with pair bias (split-bf16, ~fp32 accurate).
// Block: 512 thr = 8 waves = 4 heads x 2 k-split waves; qtile=32.
// Grid 256 = (2 hh) x (2 b x 64 qt), hh-siblings 8 apart (same XCD L2).
// S^T = K.Q^T per 16x16 tile (full c=32 contraction in one mfma);
// softmax in C-layout (q = lane&15); P via wave-private LDS bounce to
// B-frag layout; O^T = V^T.P^T.  Bias read per-lane direct from global.
// ---------------------------------------------------------------------------
__global__ __launch_bounds__(512, 2) void attn(
    const unsigned short* __restrict__ Qh, const unsigned short* __restrict__ Ql,
    const unsigned short* __restrict__ Kh, const unsigned short* __restrict__ Kl,
    const unsigned short* __restrict__ Vth, const unsigned short* __restrict__ Vtl,
    const float* __restrict__ Bias, float* __restrict__ Y) {
  __shared__ __attribute__((aligned(16))) float Pbuf[8 * 1152];
  const int t = threadIdx.x;
  const int w = t >> 6;
  const int lane = t & 63;
  const int col = lane & 15;
  const int quad = lane >> 4;
  const int head = w >> 1;
  const int ks = w & 1;
  const int x = blockIdx.x;
  const int pp = ((x >> 4) << 3) | (x & 7);
  const int hh = (x >> 3) & 1;
  const int b = pp & 1;
  const int q0g = (pp >> 1) * 32;
  const int hg = hh * 4 + head;

  const size_t bhoff = (size_t)(b * NH + hg) * LSEQ * HW;
  const unsigned short* Qhp = Qh + bhoff;
  const unsigned short* Qlp = Ql + bhoff;
  const unsigned short* Khp = Kh + bhoff;
  const unsigned short* Klp = Kl + bhoff;
  const unsigned short* Vhp = Vth + bhoff;
  const unsigned short* Vlp = Vtl + bhoff;
  float* Pw = &Pbuf[w * 1152];

  // Q B-frags: lane holds Q[q = qt*16+col][c = quad*8+j]
  bf16x8 Qbh[2], Qbl[2];
#pragma unroll
  for (int qt = 0; qt < 2; ++qt) {
    size_t off = (size_t)(q0g + qt * 16 + col) * HW + quad * 8;
    Qbh[qt] = *(const bf16x8*)(Qhp + off);
    Qbl[qt] = *(const bf16x8*)(Qlp + off);
  }

  f32x4 o[2][2];
#pragma unroll
  for (int ct = 0; ct < 2; ++ct)
#pragma unroll
    for (int qt = 0; qt < 2; ++qt)
#pragma unroll
      for (int r = 0; r < 4; ++r) o[ct][qt][r] = 0.f;
  float m_i[2] = {-1e30f, -1e30f}, l_i[2] = {0.f, 0.f};

  const float* bq[2];
#pragma unroll
  for (int qt = 0; qt < 2; ++qt)
    bq[qt] = Bias + (size_t)(b * LSEQ + q0g + qt * 16 + col) * LSEQ * NH + hg;

  // preload K frags + bias for first tile
  int kb = ks * 32;
  bf16x8 Kah[2], Kal[2];
  float bp[2][2][4];
#pragma unroll
  for (int kt = 0; kt < 2; ++kt) {
    size_t off = (size_t)(kb + kt * 16 + col) * HW + quad * 8;
    Kah[kt] = *(const bf16x8*)(Khp + off);
    Kal[kt] = *(const bf16x8*)(Klp + off);
  }
#pragma unroll
  for (int kt = 0; kt < 2; ++kt)
#pragma unroll
    for (int qt = 0; qt < 2; ++qt)
#pragma unroll
      for (int r = 0; r < 4; ++r)
        bp[kt][qt][r] = bq[qt][(size_t)(kb + kt * 16 + quad * 4 + r) * NH];

#pragma unroll 1
  for (int it = 0; it < 32; ++it) {
    const int kbn = (it < 31) ? kb + 64 : kb;
    // V A-frags for this tile (consumed at the end -> latency hidden)
    bf16x8 Vah[2], Val[2];
#pragma unroll
    for (int ct = 0; ct < 2; ++ct) {
      size_t off = (size_t)(ct * 16 + col) * LSEQ + kb + quad * 8;
      Vah[ct] = *(const bf16x8*)(Vhp + off);
      Val[ct] = *(const bf16x8*)(Vlp + off);
    }
    // S^T = K.Q^T (hi*hi + hi*lo + lo*hi)
    f32x4 s[2][2];
#pragma unroll
    for (int kt = 0; kt < 2; ++kt)
#pragma unroll
      for (int qt = 0; qt < 2; ++qt) {
        f32x4 a = {0.f, 0.f, 0.f, 0.f};
        a = __builtin_amdgcn_mfma_f32_16x16x32_bf16(Kah[kt], Qbh[qt], a, 0, 0, 0);
        a = __builtin_amdgcn_mfma_f32_16x16x32_bf16(Kah[kt], Qbl[qt], a, 0, 0, 0);
        a = __builtin_amdgcn_mfma_f32_16x16x32_bf16(Kal[kt], Qbh[qt], a, 0, 0, 0);
        s[kt][qt] = a;
      }
#pragma unroll
    for (int kt = 0; kt < 2; ++kt)
#pragma unroll
      for (int qt = 0; qt < 2; ++qt)
#pragma unroll
        for (int r = 0; r < 4; ++r) s[kt][qt][r] += bp[kt][qt][r];
    // prefetch next K frags + bias
#pragma unroll
    for (int kt = 0; kt < 2; ++kt) {
      size_t off = (size_t)(kbn + kt * 16 + col) * HW + quad * 8;
      Kah[kt] = *(const bf16x8*)(Khp + off);
      Kal[kt] = *(const bf16x8*)(Klp + off);
    }
#pragma unroll
    for (int kt = 0; kt < 2; ++kt)
#pragma unroll
      for (int qt = 0; qt < 2; ++qt)
#pragma unroll
        for (int r = 0; r < 4; ++r)
          bp[kt][qt][r] = bq[qt][(size_t)(kbn + kt * 16 + quad * 4 + r) * NH];
    // online softmax per qt (row = q = col, spread over quads via xor16/32)
#pragma unroll
    for (int qt = 0; qt < 2; ++qt) {
      float mx = s[0][qt][0];
#pragma unroll
      for (int r = 1; r < 4; ++r) mx = fmaxf(mx, s[0][qt][r]);
#pragma unroll
      for (int r = 0; r < 4; ++r) mx = fmaxf(mx, s[1][qt][r]);
      mx = fmaxf(mx, __shfl_xor(mx, 16, 64));
      mx = fmaxf(mx, __shfl_xor(mx, 32, 64));
      float mnew = fmaxf(m_i[qt], mx);
      float al = __expf(m_i[qt] - mnew);
      float ps = 0.f;
#pragma unroll
      for (int kt = 0; kt < 2; ++kt)
#pragma unroll
        for (int r = 0; r < 4; ++r) {
          float p = __expf(s[kt][qt][r] - mnew);
          s[kt][qt][r] = p;
          ps += p;
        }
      ps += __shfl_xor(ps, 16, 64);
      ps += __shfl_xor(ps, 32, 64);
      l_i[qt] = l_i[qt] * al + ps;
      m_i[qt] = mnew;
#pragma unroll
      for (int ct = 0; ct < 2; ++ct)
#pragma unroll
        for (int r = 0; r < 4; ++r) o[ct][qt][r] *= al;
    }
    // P C-layout -> LDS (wave-private, no barrier needed)
#pragma unroll
    for (int kt = 0; kt < 2; ++kt)
#pragma unroll
      for (int qt = 0; qt < 2; ++qt)
#pragma unroll
        for (int r = 0; r < 4; ++r)
          Pw[(kt * 16 + quad * 4 + r) * 34 + qt * 16 + col] = s[kt][qt][r];
    // read back as B-frags (P^T[k=quad*8+j][q=col]) with hi/lo split
    bf16x8 Pbh[2], Pbl[2];
#pragma unroll
    for (int qt = 0; qt < 2; ++qt) {
#pragma unroll
      for (int j = 0; j < 8; ++j) {
        float p = Pw[(quad * 8 + j) * 34 + qt * 16 + col];
        unsigned short hs = f2bf(p);
        Pbh[qt][j] = (short)hs;
        Pbl[qt][j] = (short)f2bf(p - bf2f(hs));
      }
    }
    // O^T += V^T . P^T
#pragma unroll
    for (int ct = 0; ct < 2; ++ct)
#pragma unroll
      for (int qt = 0; qt < 2; ++qt) {
        f32x4 a = o[ct][qt];
        a = __builtin_amdgcn_mfma_f32_16x16x32_bf16(Vah[ct], Pbh[qt], a, 0, 0, 0);
        a = __builtin_amdgcn_mfma_f32_16x16x32_bf16(Vah[ct], Pbl[qt], a, 0, 0, 0);
        a = __builtin_amdgcn_mfma_f32_16x16x32_bf16(Val[ct], Pbh[qt], a, 0, 0, 0);
        o[ct][qt] = a;
      }
    kb += 64;
  }

  // ---- merge the two k-split waves of each head ----
  __syncthreads();
  if (ks == 1) {
#pragma unroll
    for (int ct = 0; ct < 2; ++ct)
#pragma unroll
      for (int qt = 0; qt < 2; ++qt)
#pragma unroll
        for (int r = 0; r < 4; ++r)
          Pw[(ct * 16 + quad * 4 + r) * 34 + qt * 16 + col] = o[ct][qt][r];
    if (quad == 0) {
#pragma unroll
      for (int qt = 0; qt < 2; ++qt) {
        Pw[1088 + qt * 16 + col] = m_i[qt];
        Pw[1120 + qt * 16 + col] = l_i[qt];
      }
    }
  }
  __syncthreads();
  if (ks == 0) {
    const float* Pp = Pw + 1152;  // partner wave (same head, ks=1)
#pragma unroll
    for (int qt = 0; qt < 2; ++qt) {
      float m2 = Pp[1088 + qt * 16 + col];
      float l2 = Pp[1120 + qt * 16 + col];
      float mm = fmaxf(m_i[qt], m2);
      float a1 = __expf(m_i[qt] - mm);
      float a2 = __expf(m2 - mm);
      float inv = 1.0f / (l_i[qt] * a1 + l2 * a2);
#pragma unroll
      for (int ct = 0; ct < 2; ++ct) {
        float4 res;
        float* rp = &res.x;
#pragma unroll
        for (int r = 0; r < 4; ++r) {
          float oo = o[ct][qt][r] * a1 +
                     Pp[(ct * 16 + quad * 4 + r) * 34 + qt * 16 + col] * a2;
          rp[r] = oo * inv;
        }
        *(float4*)&Y[(size_t)(b * LSEQ + q0g + qt * 16 + col) * EMB +
                     hg * HW + ct * 16 + quad * 4] = res;
      }
    }
  }
}

// ---------------------------------------------------------------------------
// Output projection: Out[m,n] = sum_e Y[m,e]*Wo[n,e] + bo[n].  M=4096,N=256,K=256.
// ---------------------------------------------------------------------------
__global__ __launch_bounds__(256) void out_gemm(
    const float* __restrict__ Yg, const float* __restrict__ Wo,
    const float* __restrict__ bo, float* __restrict__ Out) {
  __shared__ __attribute__((aligned(16))) float As[64 * 68];  // [k][m]
  __shared__ __attribute__((aligned(16))) float Bs[64 * 68];  // [k][n]
  const int t = threadIdx.x;
  const int tm = t >> 4, tn = t & 15;
  const int m0 = blockIdx.y * 64, n0 = blockIdx.x * 64;
  float acc[4][4] = {};
  float4 areg[4], breg[4];
#pragma unroll
  for (int u = 0; u < 4; ++u) {
    int fi = t + u * 256; int m = fi >> 4, k4 = fi & 15;
    areg[u] = *(const float4*)&Yg[(m0 + m) * 256 + k4 * 4];
    breg[u] = *(const float4*)&Wo[(n0 + m) * 256 + k4 * 4];
  }
#pragma unroll 1
  for (int s = 0; s < 4; ++s) {
    __syncthreads();
#pragma unroll
    for (int u = 0; u < 4; ++u) {
      int fi = t + u * 256; int m = fi >> 4, k4 = fi & 15;
      As[(k4 * 4 + 0) * 68 + m] = areg[u].x;
      As[(k4 * 4 + 1) * 68 + m] = areg[u].y;
      As[(k4 * 4 + 2) * 68 + m] = areg[u].z;
      As[(k4 * 4 + 3) * 68 + m] = areg[u].w;
      Bs[(k4 * 4 + 0) * 68 + m] = breg[u].x;
      Bs[(k4 * 4 + 1) * 68 + m] = breg[u].y;
      Bs[(k4 * 4 + 2) * 68 + m] = breg[u].z;
      Bs[(k4 * 4 + 3) * 68 + m] = breg[u].w;
    }
    if (s < 3) {
      int k0 = (s + 1) * 64;
#pragma unroll
      for (int u = 0; u < 4; ++u) {
        int fi = t + u * 256; int m = fi >> 4, k4 = fi & 15;
        areg[u] = *(const float4*)&Yg[(m0 + m) * 256 + k0 + k4 * 4];
        breg[u] = *(const float4*)&Wo[(n0 + m) * 256 + k0 + k4 * 4];
      }
    }
    __syncthreads();
#pragma unroll 4
    for (int kk = 0; kk < 64; ++kk) {
      float4 av = *(const float4*)&As[kk * 68 + tm * 4];
      float4 bv = *(const float4*)&Bs[kk * 68 + tn * 4];
      float am[4] = {av.x, av.y, av.z, av.w};
      float bn[4] = {bv.x, bv.y, bv.z, bv.w};
#pragma unroll
      for (int i = 0; i < 4; ++i)
#pragma unroll
        for (int j = 0; j < 4; ++j) acc[i][j] = fmaf(am[i], bn[j], acc[i][j]);
    }
  }
#pragma unroll
  for (int i = 0; i < 4; ++i) {
    int m = m0 + tm * 4 + i;
#pragma unroll
    for (int j = 0; j < 4; ++j) {
      int n = n0 + tn * 4 + j;
      Out[m * 256 + n] = acc[i][j] + bo[n];
    }
  }
}

extern "C" void kernel_launch(void* const* d_in, const int* in_sizes, int n_in,
                              void* d_out, int out_size, void* d_ws, size_t ws_size,
                              hipStream_t stream) {
  const float* X    = (const float*)d_in[0];
  const float* Bias = (const float*)d_in[1];
  const float* Wp   = (const float*)d_in[2];
  const float* Wo   = (const float*)d_in[3];
  const float* bo   = (const float*)d_in[4];
  float* Out = (float*)d_out;

  const size_t qkv_elems = (size_t)BB * NH * LSEQ * HW;  // 1,048,576
  unsigned short* Qh  = (unsigned short*)d_ws;
  unsigned short* Ql  = Qh + qkv_elems;
  unsigned short* Kh  = Ql + qkv_elems;
  unsigned short* Kl  = Kh + qkv_elems;
  unsigned short* Vth = Kl + qkv_elems;
  unsigned short* Vtl = Vth + qkv_elems;
  float* Yw = (float*)(Vtl + qkv_elems);  // 4096 x 256 fp32

  qkv_gemm<<<dim3(12, 32), 256, 0, stream>>>(X, Wp, Qh, Ql, Kh, Kl, Vth, Vtl);
  attn<<<dim3(256), 512, 0, stream>>>(Qh, Ql, Kh, Kl, Vth, Vtl, Bias, Yw);
  out_gemm<<<dim3(4, 64), 256, 0, stream>>>(Yw, Wo, bo, Out);
}

// Round 4
// 459.296 us; speedup vs baseline: 1.7243x; 1.2837x over previous
//
#include <hip/hip_runtime.h>
#include <math.h>

#define NH   8
#define HW   32
#define LSEQ 2048
#define EMB  256
#define BB   2

typedef short bf16x8 __attribute__((ext_vector_type(8)));
typedef float f32x4  __attribute__((ext_vector_type(4)));

__device__ __forceinline__ unsigned short f2bf(float x) {  // RNE
  union { float f; unsigned u; } v; v.f = x;
  unsigned r = v.u + 0x7fffu + ((v.u >> 16) & 1u);
  return (unsigned short)(r >> 16);
}
__device__ __forceinline__ float bf2f(unsigned short h) {
  union { float f; unsigned u; } v; v.u = ((unsigned)h) << 16;
  return v.f;
}
__device__ __forceinline__ void split2(float x, unsigned short& h, unsigned short& l) {
  h = f2bf(x);
  l = f2bf(x - bf2f(h));
}

// ---------------------------------------------------------------------------
// QKV projection, split-bf16 MFMA, LDS-free.
// Block 256 thr = 4 waves stacked on m; wave = 16m x 64n; grid (12, 64).
// A = X[m][e] (lane: m=col, e=quad*8+j), B = Wp[f][e] (f=col) -> D[m][f].
// Outputs: Qh/Ql,Kh/Kl [b][h][l][32] (Q scaled), Vth/Vtl [b][h][c][2048].
// ---------------------------------------------------------------------------
__global__ __launch_bounds__(256, 4) void qkv_gemm(
    const float* __restrict__ X, const float* __restrict__ Wp,
    unsigned short* __restrict__ Qh, unsigned short* __restrict__ Ql,
    unsigned short* __restrict__ Kh, unsigned short* __restrict__ Kl,
    unsigned short* __restrict__ Vth, unsigned short* __restrict__ Vtl) {
  const int t = threadIdx.x;
  const int w = t >> 6, lane = t & 63;
  const int col = lane & 15, quad = lane >> 4;
  const int m0 = blockIdx.y * 64 + w * 16;
  const int n0 = blockIdx.x * 64;
  const float* xrow = X + (size_t)(m0 + col) * 256 + quad * 8;

  f32x4 acc[4];
#pragma unroll
  for (int nt = 0; nt < 4; ++nt) acc[nt] = (f32x4){0.f, 0.f, 0.f, 0.f};

#pragma unroll
  for (int es = 0; es < 8; ++es) {
    float4 xa = *(const float4*)(xrow + es * 32);
    float4 xb = *(const float4*)(xrow + es * 32 + 4);
    float xv[8] = {xa.x, xa.y, xa.z, xa.w, xb.x, xb.y, xb.z, xb.w};
    bf16x8 ah, al;
#pragma unroll
    for (int j = 0; j < 8; ++j) {
      unsigned short hi, lo; split2(xv[j], hi, lo);
      ah[j] = (short)hi; al[j] = (short)lo;
    }
#pragma unroll
    for (int nt = 0; nt < 4; ++nt) {
      const float* wrow = Wp + (size_t)(n0 + nt * 16 + col) * 256 + es * 32 + quad * 8;
      float4 wa = *(const float4*)(wrow);
      float4 wb = *(const float4*)(wrow + 4);
      float wv[8] = {wa.x, wa.y, wa.z, wa.w, wb.x, wb.y, wb.z, wb.w};
      bf16x8 bh, bl;
#pragma unroll
      for (int j = 0; j < 8; ++j) {
        unsigned short hi, lo; split2(wv[j], hi, lo);
        bh[j] = (short)hi; bl[j] = (short)lo;
      }
      acc[nt] = __builtin_amdgcn_mfma_f32_16x16x32_bf16(ah, bh, acc[nt], 0, 0, 0);
      acc[nt] = __builtin_amdgcn_mfma_f32_16x16x32_bf16(ah, bl, acc[nt], 0, 0, 0);
      acc[nt] = __builtin_amdgcn_mfma_f32_16x16x32_bf16(al, bh, acc[nt], 0, 0, 0);
    }
  }

  const float qscale = 0.17677669529663687f;  // 32^-0.5
#pragma unroll
  for (int nt = 0; nt < 4; ++nt) {
    const int f = n0 + nt * 16 + col;
    const int hd = f / 96, r0 = f - hd * 96;
#pragma unroll
    for (int r = 0; r < 4; ++r) {
      const int m = m0 + quad * 4 + r;
      const int bbv = m >> 11, ll = m & 2047;
      float v = acc[nt][r];
      unsigned short hi, lo;
      if (r0 < 64) {
        float sv = (r0 < 32) ? v * qscale : v;
        split2(sv, hi, lo);
        size_t idx = ((size_t)(bbv * NH + hd) * LSEQ + ll) * HW + (r0 & 31);
        if (r0 < 32) { Qh[idx] = hi; Ql[idx] = lo; }
        else         { Kh[idx] = hi; Kl[idx] = lo; }
      } else {
        split2(v, hi, lo);
        size_t idx = ((size_t)(bbv * NH + hd) * HW + (r0 - 64)) * LSEQ + ll;
        Vth[idx] = hi; Vtl[idx] = lo;
      }
    }
  }
}

// ---------------------------------------------------------------------------
// MFMA flash attention with pair bias, k-split across blocks.
// Grid 512: p=(qt,b,ks) with hh-sibling (x^8) on same XCD for bias line share.
// Block 512 thr = 8 waves = 4 heads x 2 wks; block k-range 1024; 16 iters of
// 64-k tiles.  Bias tile staged to LDS [h][q][k] (coalesced float4 global
// loads, reg-prefetched 1 tile ahead); lane reads one ds_read_b128 -> used as
// MFMA C-initializer.  Partial (o,m,l) to workspace; merged in out_gemm.
// ---------------------------------------------------------------------------
__global__ __launch_bounds__(512, 4) void attn(
    const unsigned short* __restrict__ Qh, const unsigned short* __restrict__ Ql,
    const unsigned short* __restrict__ Kh, const unsigned short* __restrict__ Kl,
    const unsigned short* __restrict__ Vth, const unsigned short* __restrict__ Vtl,
    const float* __restrict__ Bias, float* __restrict__ Yp,
    float* __restrict__ Mm, float* __restrict__ Ll) {
  __shared__ __attribute__((aligned(16))) float Bst[4 * 32 * 72];  // [h][q][k] 36.9KB
  __shared__ __attribute__((aligned(16))) float Pbuf[8 * 1152];    // per-wave  36.9KB
  const int t = threadIdx.x;
  const int w = t >> 6, lane = t & 63;
  const int col = lane & 15, quad = lane >> 4;
  const int head = w >> 1, wks = w & 1;
  const int x = blockIdx.x;
  const int p = ((x >> 4) << 3) | (x & 7);
  const int hh = (x >> 3) & 1;
  const int ks = p & 1;
  const int b = (p >> 1) & 1;
  const int q0g = (p >> 2) * 32;
  const int hg = hh * 4 + head;
  const int kbase = ks * 1024;

  const size_t bhoff = (size_t)(b * NH + hg) * LSEQ * HW;
  const unsigned short* Qhp = Qh + bhoff;
  const unsigned short* Qlp = Ql + bhoff;
  const unsigned short* Khp = Kh + bhoff;
  const unsigned short* Klp = Kl + bhoff;
  const unsigned short* Vhp = Vth + bhoff;
  const unsigned short* Vlp = Vtl + bhoff;
  float* Pw = &Pbuf[w * 1152];

  // Q B-frags (q=col, c=quad*8+j)
  bf16x8 Qbh[2], Qbl[2];
#pragma unroll
  for (int qt = 0; qt < 2; ++qt) {
    size_t off = (size_t)(q0g + qt * 16 + col) * HW + quad * 8;
    Qbh[qt] = *(const bf16x8*)(Qhp + off);
    Qbl[qt] = *(const bf16x8*)(Qlp + off);
  }

  f32x4 o[2][2];
#pragma unroll
  for (int ct = 0; ct < 2; ++ct)
#pragma unroll
    for (int qt = 0; qt < 2; ++qt) o[ct][qt] = (f32x4){0.f, 0.f, 0.f, 0.f};
  float m_i[2] = {-1e30f, -1e30f}, l_i[2] = {0.f, 0.f};

  // staging index (thread-uniform per u): q = u*8 + w, k = lane
  const int sq = w, sk = lane;
  // prefetch bias tile 0
  float4 bsr[4];
#pragma unroll
  for (int u = 0; u < 4; ++u)
    bsr[u] = *(const float4*)&Bias[(((size_t)(b * LSEQ + q0g + u * 8 + sq)) * LSEQ +
                                    kbase + sk) * NH + hh * 4];

#pragma unroll 1
  for (int it = 0; it < 16; ++it) {
    __syncthreads();  // prior reads of Bst done
#pragma unroll
    for (int u = 0; u < 4; ++u) {
      const int qq = u * 8 + sq;
      Bst[0 * 2304 + qq * 72 + sk] = bsr[u].x;
      Bst[1 * 2304 + qq * 72 + sk] = bsr[u].y;
      Bst[2 * 2304 + qq * 72 + sk] = bsr[u].z;
      Bst[3 * 2304 + qq * 72 + sk] = bsr[u].w;
    }
    const int kw = kbase + it * 64 + wks * 32;
    // K (A-frag: k=col) and V^T (A-frag: c=col) loads for this tile
    bf16x8 Kah[2], Kal[2], Vah[2], Val[2];
#pragma unroll
    for (int kt = 0; kt < 2; ++kt) {
      size_t off = (size_t)(kw + kt * 16 + col) * HW + quad * 8;
      Kah[kt] = *(const bf16x8*)(Khp + off);
      Kal[kt] = *(const bf16x8*)(Klp + off);
    }
#pragma unroll
    for (int ct = 0; ct < 2; ++ct) {
      size_t off = (size_t)(ct * 16 + col) * LSEQ + kw + quad * 8;
      Vah[ct] = *(const bf16x8*)(Vhp + off);
      Val[ct] = *(const bf16x8*)(Vlp + off);
    }
    if (it < 15) {
#pragma unroll
      for (int u = 0; u < 4; ++u)
        bsr[u] = *(const float4*)&Bias[(((size_t)(b * LSEQ + q0g + u * 8 + sq)) * LSEQ +
                                        kbase + (it + 1) * 64 + sk) * NH + hh * 4];
    }
    __syncthreads();  // Bst visible

    // S^T = K.Q^T with C initialized to bias (bias[q=col][k=quad*4+r])
    f32x4 s[2][2];
#pragma unroll
    for (int kt = 0; kt < 2; ++kt)
#pragma unroll
      for (int qt = 0; qt < 2; ++qt) {
        f32x4 a = *(const f32x4*)&Bst[head * 2304 + (qt * 16 + col) * 72 +
                                      wks * 32 + kt * 16 + quad * 4];
        a = __builtin_amdgcn_mfma_f32_16x16x32_bf16(Kah[kt], Qbh[qt], a, 0, 0, 0);
        a = __builtin_amdgcn_mfma_f32_16x16x32_bf16(Kah[kt], Qbl[qt], a, 0, 0, 0);
        a = __builtin_amdgcn_mfma_f32_16x16x32_bf16(Kal[kt], Qbh[qt], a, 0, 0, 0);
        s[kt][qt] = a;
      }

    // online softmax (row = q = col; spread over quads via xor 16/32)
    float alpha[2];
#pragma unroll
    for (int qt = 0; qt < 2; ++qt) {
      float mx = s[0][qt][0];
#pragma unroll
      for (int r = 1; r < 4; ++r) mx = fmaxf(mx, s[0][qt][r]);
#pragma unroll
      for (int r = 0; r < 4; ++r) mx = fmaxf(mx, s[1][qt][r]);
      mx = fmaxf(mx, __shfl_xor(mx, 16, 64));
      mx = fmaxf(mx, __shfl_xor(mx, 32, 64));
      float mnew = fmaxf(m_i[qt], mx);
      float al = __expf(m_i[qt] - mnew);
      float ps = 0.f;
#pragma unroll
      for (int kt = 0; kt < 2; ++kt)
#pragma unroll
        for (int r = 0; r < 4; ++r) {
          float pv = __expf(s[kt][qt][r] - mnew);
          s[kt][qt][r] = pv;
          ps += pv;
        }
      ps += __shfl_xor(ps, 16, 64);
      ps += __shfl_xor(ps, 32, 64);
      l_i[qt] = l_i[qt] * al + ps;
      m_i[qt] = mnew;
      alpha[qt] = al;
#pragma unroll
      for (int ct = 0; ct < 2; ++ct)
#pragma unroll
        for (int r = 0; r < 4; ++r) o[ct][qt][r] *= al;
    }

    // P bounce: C-layout -> LDS (wave-private) -> B-frag with hi/lo split
#pragma unroll
    for (int kt = 0; kt < 2; ++kt)
#pragma unroll
      for (int qt = 0; qt < 2; ++qt)
#pragma unroll
        for (int r = 0; r < 4; ++r)
          Pw[(kt * 16 + quad * 4 + r) * 34 + qt * 16 + col] = s[kt][qt][r];
    bf16x8 Pbh[2], Pbl[2];
#pragma unroll
    for (int qt = 0; qt < 2; ++qt) {
#pragma unroll
      for (int j = 0; j < 8; ++j) {
        float pv = Pw[(quad * 8 + j) * 34 + qt * 16 + col];
        unsigned short hi, lo; split2(pv, hi, lo);
        Pbh[qt][j] = (short)hi; Pbl[qt][j] = (short)lo;
      }
    }
    // O^T += V^T . P^T
#pragma unroll
    for (int ct = 0; ct < 2; ++ct)
#pragma unroll
      for (int qt = 0; qt < 2; ++qt) {
        f32x4 a = o[ct][qt];
        a = __builtin_amdgcn_mfma_f32_16x16x32_bf16(Vah[ct], Pbh[qt], a, 0, 0, 0);
        a = __builtin_amdgcn_mfma_f32_16x16x32_bf16(Vah[ct], Pbl[qt], a, 0, 0, 0);
        a = __builtin_amdgcn_mfma_f32_16x16x32_bf16(Val[ct], Pbh[qt], a, 0, 0, 0);
        o[ct][qt] = a;
      }
  }

  // ---- merge the two wks waves of each head; store partials ----
  __syncthreads();
  if (wks == 1) {
#pragma unroll
    for (int ct = 0; ct < 2; ++ct)
#pragma unroll
      for (int qt = 0; qt < 2; ++qt)
#pragma unroll
        for (int r = 0; r < 4; ++r)
          Pw[(ct * 16 + quad * 4 + r) * 34 + qt * 16 + col] = o[ct][qt][r];
    if (quad == 0) {
#pragma unroll
      for (int qt = 0; qt < 2; ++qt) {
        Pw[1088 + qt * 16 + col] = m_i[qt];
        Pw[1120 + qt * 16 + col] = l_i[qt];
      }
    }
  }
  __syncthreads();
  if (wks == 0) {
    const float* Pp = Pw + 1152;  // partner (same head, wks=1)
#pragma unroll
    for (int qt = 0; qt < 2; ++qt) {
      float m2 = Pp[1088 + qt * 16 + col];
      float l2 = Pp[1120 + qt * 16 + col];
      float mm = fmaxf(m_i[qt], m2);
      float a1 = __expf(m_i[qt] - mm);
      float a2 = __expf(m2 - mm);
      float lm = l_i[qt] * a1 + l2 * a2;
      const size_t row = (size_t)ks * 4096 + b * LSEQ + q0g + qt * 16 + col;
      if (quad == 0) {
        Mm[row * 8 + hg] = mm;
        Ll[row * 8 + hg] = lm;
      }
#pragma unroll
      for (int ct = 0; ct < 2; ++ct) {
        float4 res;
        res.x = o[ct][qt][0] * a1 + Pp[(ct * 16 + quad * 4 + 0) * 34 + qt * 16 + col] * a2;
        res.y = o[ct][qt][1] * a1 + Pp[(ct * 16 + quad * 4 + 1) * 34 + qt * 16 + col] * a2;
        res.z = o[ct][qt][2] * a1 + Pp[(ct * 16 + quad * 4 + 2) * 34 + qt * 16 + col] * a2;
        res.w = o[ct][qt][3] * a1 + Pp[(ct * 16 + quad * 4 + 3) * 34 + qt * 16 + col] * a2;
        *(float4*)&Yp[row * EMB + hg * HW + ct * 16 + quad * 4] = res;
      }
    }
  }
}

// ---------------------------------------------------------------------------
// Output projection with fused k-split merge.  Split-bf16 MFMA, LDS-free.
// Block 256 = 4 waves on m; wave 16m x 64n; grid (4, 64).
// A[m][e] = merged y (from Yp/Mm/Ll partials, computed on the fly);
// B[f][e] = Wo.  Out += bo.
// ---------------------------------------------------------------------------
__global__ __launch_bounds__(256, 4) void out_gemm(
    const float* __restrict__ Yp, const float* __restrict__ Mm,
    const float* __restrict__ Ll, const float* __restrict__ Wo,
    const float* __restrict__ bo, float* __restrict__ Out) {
  const int t = threadIdx.x;
  const int w = t >> 6, lane = t & 63;
  const int col = lane & 15, quad = lane >> 4;
  const int m0 = blockIdx.y * 64 + w * 16;
  const int n0 = blockIdx.x * 64;
  const int grow = m0 + col;
  const float* o1p = Yp + (size_t)grow * 256 + quad * 8;
  const float* o2p = o1p + (size_t)4096 * 256;

  f32x4 acc[4];
#pragma unroll
  for (int nt = 0; nt < 4; ++nt) acc[nt] = (f32x4){0.f, 0.f, 0.f, 0.f};

#pragma unroll
  for (int es = 0; es < 8; ++es) {  // es == head
    float m1 = Mm[(size_t)grow * 8 + es];
    float l1 = Ll[(size_t)grow * 8 + es];
    float m2 = Mm[(size_t)(4096 + grow) * 8 + es];
    float l2 = Ll[(size_t)(4096 + grow) * 8 + es];
    float M = fmaxf(m1, m2);
    float w1 = __expf(m1 - M), w2 = __expf(m2 - M);
    float inv = 1.0f / (l1 * w1 + l2 * w2);
    w1 *= inv; w2 *= inv;
    float4 a1 = *(const float4*)(o1p + es * 32);
    float4 b1 = *(const float4*)(o1p + es * 32 + 4);
    float4 a2 = *(const float4*)(o2p + es * 32);
    float4 b2 = *(const float4*)(o2p + es * 32 + 4);
    float yv[8] = {a1.x * w1 + a2.x * w2, a1.y * w1 + a2.y * w2,
                   a1.z * w1 + a2.z * w2, a1.w * w1 + a2.w * w2,
                   b1.x * w1 + b2.x * w2, b1.y * w1 + b2.y * w2,
                   b1.z * w1 + b2.z * w2, b1.w * w1 + b2.w * w2};
    bf16x8 ah, al;
#pragma unroll
    for (int j = 0; j < 8; ++j) {
      unsigned short hi, lo; split2(yv[j], hi, lo);
      ah[j] = (short)hi; al[j] = (short)lo;
    }
#pragma unroll
    for (int nt = 0; nt < 4; ++nt) {
      const float* wrow = Wo + (size_t)(n0 + nt * 16 + col) * 256 + es * 32 + quad * 8;
      float4 wa = *(const float4*)(wrow);
      float4 wb = *(const float4*)(wrow + 4);
      float wv[8] = {wa.x, wa.y, wa.z, wa.w, wb.x, wb.y, wb.z, wb.w};
      bf16x8 bh, bl;
#pragma unroll
      for (int j = 0; j < 8; ++j) {
        unsigned short hi, lo; split2(wv[j], hi, lo);
        bh[j] = (short)hi; bl[j] = (short)lo;
      }
      acc[nt] = __builtin_amdgcn_mfma_f32_16x16x32_bf16(ah, bh, acc[nt], 0, 0, 0);
      acc[nt] = __builtin_amdgcn_mfma_f32_16x16x32_bf16(ah, bl, acc[nt], 0, 0, 0);
      acc[nt] = __builtin_amdgcn_mfma_f32_16x16x32_bf16(al, bh, acc[nt], 0, 0, 0);
    }
  }
#pragma unroll
  for (int nt = 0; nt < 4; ++nt) {
    const int f = n0 + nt * 16 + col;
    const float bias_o = bo[f];
#pragma unroll
    for (int r = 0; r < 4; ++r)
      Out[(size_t)(m0 + quad * 4 + r) * 256 + f] = acc[nt][r] + bias_o;
  }
}

extern "C" void kernel_launch(void* const* d_in, const int* in_sizes, int n_in,
                              void* d_out, int out_size, void* d_ws, size_t ws_size,
                              hipStream_t stream) {
  const float* X    = (const float*)d_in[0];
  const float* Bias = (const float*)d_in[1];
  const float* Wp   = (const float*)d_in[2];
  const float* Wo   = (const float*)d_in[3];
  const float* bo   = (const float*)d_in[4];
  float* Out = (float*)d_out;

  const size_t qkv_elems = (size_t)BB * NH * LSEQ * HW;  // 1,048,576
  unsigned short* Qh  = (unsigned short*)d_ws;
  unsigned short* Ql  = Qh + qkv_elems;
  unsigned short* Kh  = Ql + qkv_elems;
  unsigned short* Kl  = Kh + qkv_elems;
  unsigned short* Vth = Kl + qkv_elems;
  unsigned short* Vtl = Vth + qkv_elems;
  float* Yp = (float*)(Vtl + qkv_elems);     // [2ks][4096][256] fp32 = 8 MB
  float* Mm = Yp + (size_t)2 * 4096 * 256;   // [2ks][4096][8]
  float* Ll = Mm + (size_t)2 * 4096 * 8;     // [2ks][4096][8]

  qkv_gemm<<<dim3(12, 64), 256, 0, stream>>>(X, Wp, Qh, Ql, Kh, Kl, Vth, Vtl);
  attn<<<dim3(512), 512, 0, stream>>>(Qh, Ql, Kh, Kl, Vth, Vtl, Bias, Yp, Mm, Ll);
  out_gemm<<<dim3(4, 64), 256, 0, stream>>>(Yp, Mm, Ll, Wo, bo, Out);
}